// Round 3
// baseline (21298.466 us; speedup 1.0000x reference)
//
#include <hip/hip_runtime.h>
#include <hip/hip_bf16.h>
#include <math.h>

// Problem constants
#define Bc 2
#define Tc 4096
#define Dc 1024
#define Hc 16
#define DKc 64
#define DVc 128
#define KDIMc 1024   // H*DK
#define VDIMc 2048   // H*DV
#define Mrows (Bc*Tc) // 8192
#define CC 64        // scan chunk size
#define NCH (Tc/CC)  // 64 chunks

__device__ __forceinline__ float siluf(float x) {
    return x / (1.f + expf(-x));
}

// ---------------------------------------------------------------------------
// Generic tiled f32 GEMM: C[M,N] = A[M,K] @ B[K,N], all row-major.
// ---------------------------------------------------------------------------
#define GBM 64
#define GBN 64
#define GBK 16
__global__ void __launch_bounds__(256) gemm_f32(
    const float* __restrict__ A, const float* __restrict__ B,
    float* __restrict__ C, int M, int N, int K) {
    __shared__ float As[GBK][GBM + 4];
    __shared__ float Bs[GBK][GBN];
    const int tid = threadIdx.x;
    const int nbx = N / GBN;
    const int bx = blockIdx.x % nbx;
    const int by = blockIdx.x / nbx;
    const int row0 = by * GBM, col0 = bx * GBN;
    const int ty = tid >> 4, tx = tid & 15;
    const int ar = tid >> 2, ak = (tid & 3) * 4;
    const int bc = tid & 63, bk0 = (tid >> 6) * 4;

    float acc[4][4];
#pragma unroll
    for (int i = 0; i < 4; i++)
#pragma unroll
        for (int j = 0; j < 4; j++) acc[i][j] = 0.f;

    for (int k0 = 0; k0 < K; k0 += GBK) {
        float4 av = *(const float4*)&A[(size_t)(row0 + ar) * K + k0 + ak];
        As[ak + 0][ar] = av.x;
        As[ak + 1][ar] = av.y;
        As[ak + 2][ar] = av.z;
        As[ak + 3][ar] = av.w;
#pragma unroll
        for (int i = 0; i < 4; i++)
            Bs[bk0 + i][bc] = B[(size_t)(k0 + bk0 + i) * N + col0 + bc];
        __syncthreads();
#pragma unroll
        for (int kk = 0; kk < GBK; kk++) {
            float a[4], b[4];
            *(float4*)a = *(const float4*)&As[kk][ty * 4];
            *(float4*)b = *(const float4*)&Bs[kk][tx * 4];
#pragma unroll
            for (int i = 0; i < 4; i++)
#pragma unroll
                for (int j = 0; j < 4; j++) acc[i][j] += a[i] * b[j];
        }
        __syncthreads();
    }
#pragma unroll
    for (int i = 0; i < 4; i++) {
        float4 v = make_float4(acc[i][0], acc[i][1], acc[i][2], acc[i][3]);
        *(float4*)&C[(size_t)(row0 + ty * 4 + i) * N + col0 + tx * 4] = v;
    }
}

// ---------------------------------------------------------------------------
// a/b projections (N=16 each) fused with softplus/sigmoid -> g, beta.
// ---------------------------------------------------------------------------
__global__ void __launch_bounds__(256) ab_proj(
    const float* __restrict__ x, const float* __restrict__ w_a,
    const float* __restrict__ w_b, const float* __restrict__ A_log,
    const float* __restrict__ dt_bias, float* __restrict__ g_out,
    float* __restrict__ beta_out) {
    const int row = blockIdx.x * 4 + (threadIdx.x >> 6);
    const int lane = threadIdx.x & 63;
    const int h = lane >> 2;
    const int kg = lane & 3;
    const float* xr = x + (size_t)row * Dc;
    float pa = 0.f, pb = 0.f;
    const int kbeg = kg * 256, kend = kbeg + 256;
    for (int k = kbeg; k < kend; k++) {
        float xv = xr[k];
        pa += xv * w_a[k * Hc + h];
        pb += xv * w_b[k * Hc + h];
    }
    pa += __shfl_xor(pa, 1, 64);
    pa += __shfl_xor(pa, 2, 64);
    pb += __shfl_xor(pb, 1, 64);
    pb += __shfl_xor(pb, 2, 64);
    if (kg == 0) {
        float arg = pa + dt_bias[h];
        float sp = fmaxf(arg, 0.f) + log1pf(expf(-fabsf(arg)));
        g_out[(size_t)row * Hc + h] = -expf(A_log[h]) * sp;
        beta_out[(size_t)row * Hc + h] = 2.f / (1.f + expf(-pb));
    }
}

// ---------------------------------------------------------------------------
// Save 3-row halos at 64-step chunk boundaries (for in-place conv).
// ---------------------------------------------------------------------------
template <int C>
__global__ void __launch_bounds__(256) save_halo(
    const float* __restrict__ in, float* __restrict__ halo) {
    const int g = blockIdx.x * 256 + threadIdx.x;
    const int total = Bc * (Tc / 64 - 1) * 3 * C;
    if (g >= total) return;
    const int c = g % C;
    int r = g / C;
    const int j = r % 3;
    r /= 3;
    const int chunk = r % (Tc / 64 - 1) + 1;
    const int b = r / (Tc / 64 - 1);
    halo[((size_t)(b * 64 + chunk) * 3 + j) * C + c] =
        in[((size_t)b * Tc + chunk * 64 - 3 + j) * C + c];
}

// ---------------------------------------------------------------------------
// Depthwise causal conv1d (K=4) + SiLU (+ optional l2norm), IN PLACE.
// ---------------------------------------------------------------------------
template <int C, bool L2N>
__global__ void __launch_bounds__(256) conv_silu_inplace(
    float* __restrict__ buf, const float* __restrict__ w,
    const float* __restrict__ halo) {
    constexpr int CB = C / 256;
    const int bidx = blockIdx.x;
    const int cb = bidx % CB;
    const int tchunk = (bidx / CB) % (Tc / 64);
    const int b = bidx / (CB * (Tc / 64));
    const int c = cb * 256 + threadIdx.x;
    const int t0 = tchunk * 64;
    const float w0 = w[c * 4 + 0], w1 = w[c * 4 + 1], w2 = w[c * 4 + 2],
                w3 = w[c * 4 + 3];
    float xm3 = 0.f, xm2 = 0.f, xm1 = 0.f;
    if (tchunk > 0) {
        const float* hp = halo + (size_t)(b * 64 + tchunk) * 3 * C + c;
        xm3 = hp[0];
        xm2 = hp[C];
        xm1 = hp[2 * C];
    }
    float* p = buf + (size_t)b * Tc * C + c;
#pragma unroll 4
    for (int i = 0; i < 64; i++) {
        float xt = p[(size_t)(t0 + i) * C];
        float y = w0 * xm3 + w1 * xm2 + w2 * xm1 + w3 * xt;
        y = siluf(y);
        if (L2N) {
            float ss = y * y;
#pragma unroll
            for (int m = 1; m < 64; m <<= 1) ss += __shfl_xor(ss, m, 64);
            y *= rsqrtf(ss + 1e-6f);
        }
        p[(size_t)(t0 + i) * C] = y;
        xm3 = xm2;
        xm2 = xm1;
        xm1 = xt;
    }
}

// ---------------------------------------------------------------------------
// Chunked gated delta rule (WY form), one WG of 512 per (b,h).
// Per chunk (C=64, c=cumsum g, all exps of non-positive args):
//   A[t,s] = beta_t exp(c_t-c_s) (k_t.k_s)   (s<t)
//   RHS    = beta*(V - Gamma*(K S_in))        (Gamma_t = exp(c_t))
//   (I+A) delta = RHS   -> forward substitution
//   O      = scale*Gamma*(Q S_in) + M delta,  M[t,s]=scale exp(c_t-c_s)(q_t.k_s), s<=t
//   S_out  = exp(c_end) S_in + sum_s exp(c_end-c_s) k_s delta_s^T
// Thread (dv=tid>>2, qd=tid&3) owns S[qd*16+j][dv], j=0..15 (registers).
// ---------------------------------------------------------------------------
__global__ void __launch_bounds__(512) chunk_scan(
    const float* __restrict__ qc, const float* __restrict__ kc,
    const float* __restrict__ vc, const float* __restrict__ g,
    const float* __restrict__ beta, float* __restrict__ o) {
    const int bh = blockIdx.x;
    const int b = bh >> 4, h = bh & 15;
    const int tid = threadIdx.x;
    const int dv = tid >> 2, qd = tid & 3;

    __shared__ float kL[CC][DKc + 4];   // k rows (scaled to k-hat during P3)
    __shared__ float qL[CC][DKc + 4];
    __shared__ float kT[DKc][CC + 4];   // transposes for A/M dot products
    __shared__ float qT[DKc][CC + 4];
    __shared__ float AtL[CC][CC + 4];   // A^T (zeros on/above diag)
    __shared__ float ML[CC][CC + 4];    // M   (zeros above diag)
    __shared__ float vL[CC][DVc + 5];   // v -> RHS -> delta (stride 133, odd)
    __shared__ float cL[CC], gamL[CC], egL[CC], betaL[CC];

    float S[16];
#pragma unroll
    for (int j = 0; j < 16; j++) S[j] = 0.f;

    const size_t qk0 = (size_t)b * Tc * KDIMc + h * DKc;
    const size_t v0 = (size_t)b * Tc * VDIMc + h * DVc;
    const size_t gb0 = (size_t)b * Tc * Hc + h;

#pragma unroll 1
    for (int ch = 0; ch < NCH; ch++) {
        const int t0 = ch * CC;
        __syncthreads();  // previous chunk done reading LDS

        // ---- P0: stage k,q (64x64) + transposes, v (64x128)
#pragma unroll
        for (int i = 0; i < 2; i++) {
            int e = tid + i * 512;
            int r = e >> 4, c4 = (e & 15) << 2;
            float4 kv = *(const float4*)&kc[qk0 + (size_t)(t0 + r) * KDIMc + c4];
            float4 qv = *(const float4*)&qc[qk0 + (size_t)(t0 + r) * KDIMc + c4];
            *(float4*)&kL[r][c4] = kv;
            *(float4*)&qL[r][c4] = qv;
            kT[c4 + 0][r] = kv.x; kT[c4 + 1][r] = kv.y;
            kT[c4 + 2][r] = kv.z; kT[c4 + 3][r] = kv.w;
            qT[c4 + 0][r] = qv.x; qT[c4 + 1][r] = qv.y;
            qT[c4 + 2][r] = qv.z; qT[c4 + 3][r] = qv.w;
        }
#pragma unroll
        for (int i = 0; i < 4; i++) {
            int e = tid + i * 512;
            int r = e >> 5, c4 = (e & 31) << 2;
            float4 vv = *(const float4*)&vc[v0 + (size_t)(t0 + r) * VDIMc + c4];
            vL[r][c4 + 0] = vv.x; vL[r][c4 + 1] = vv.y;
            vL[r][c4 + 2] = vv.z; vL[r][c4 + 3] = vv.w;
        }
        // ---- P1: wave 0: cumsum(g), decay factors, beta
        if (tid < 64) {
            float gv = g[gb0 + (size_t)(t0 + tid) * Hc];
            float cv = gv;
#pragma unroll
            for (int d = 1; d < 64; d <<= 1) {
                float nb = __shfl_up(cv, d, 64);
                if (tid >= d) cv += nb;
            }
            cL[tid] = cv;
            gamL[tid] = expf(cv);
            float cend = __shfl(cv, 63, 64);
            egL[tid] = expf(cend - cv);
            betaL[tid] = beta[gb0 + (size_t)(t0 + tid) * Hc];
        }
        __syncthreads();

        // ---- P2a: A (threads 0..255) and M (threads 256..511), 4x4 tiles
        {
            const int half = tid >> 8;
            const int tt2 = tid & 255;
            const int tIdx = tt2 >> 4, sIdx = tt2 & 15;
            float dot[4][4];
#pragma unroll
            for (int i = 0; i < 4; i++)
#pragma unroll
                for (int j = 0; j < 4; j++) dot[i][j] = 0.f;
            const float(*TA)[CC + 4] = half ? qT : kT;
#pragma unroll
            for (int d = 0; d < 64; d++) {
                float4 ta = *(const float4*)&TA[d][tIdx * 4];
                float4 sa = *(const float4*)&kT[d][sIdx * 4];
                dot[0][0] += ta.x * sa.x; dot[0][1] += ta.x * sa.y;
                dot[0][2] += ta.x * sa.z; dot[0][3] += ta.x * sa.w;
                dot[1][0] += ta.y * sa.x; dot[1][1] += ta.y * sa.y;
                dot[1][2] += ta.y * sa.z; dot[1][3] += ta.y * sa.w;
                dot[2][0] += ta.z * sa.x; dot[2][1] += ta.z * sa.y;
                dot[2][2] += ta.z * sa.z; dot[2][3] += ta.z * sa.w;
                dot[3][0] += ta.w * sa.x; dot[3][1] += ta.w * sa.y;
                dot[3][2] += ta.w * sa.z; dot[3][3] += ta.w * sa.w;
            }
#pragma unroll
            for (int it = 0; it < 4; it++)
#pragma unroll
                for (int is = 0; is < 4; is++) {
                    int t = tIdx * 4 + it, s = sIdx * 4 + is;
                    if (half == 0) {
                        float v = (s < t) ? betaL[t] * expf(cL[t] - cL[s]) *
                                                dot[it][is]
                                          : 0.f;
                        AtL[s][t] = v;
                    } else {
                        float v = (s <= t) ? 0.125f * expf(cL[t] - cL[s]) *
                                                 dot[it][is]
                                           : 0.f;
                        ML[t][s] = v;
                    }
                }
        }
        // ---- P2b: RHS = beta*(v - Gamma*(k.S_in))  (in place over vL)
#pragma unroll 8
        for (int t = 0; t < 64; t++) {
            float p = 0.f;
#pragma unroll
            for (int j4 = 0; j4 < 4; j4++) {
                float4 kk = *(const float4*)&kL[t][qd * 16 + j4 * 4];
                p += kk.x * S[j4 * 4 + 0] + kk.y * S[j4 * 4 + 1] +
                     kk.z * S[j4 * 4 + 2] + kk.w * S[j4 * 4 + 3];
            }
            p += __shfl_xor(p, 1, 64);
            p += __shfl_xor(p, 2, 64);
            if (qd == 0) vL[t][dv] = betaL[t] * (vL[t][dv] - gamL[t] * p);
        }
        __syncthreads();

        // ---- P3: forward substitution (threads 0..127, column = tid);
        //          threads 128+ scale kL -> k-hat meanwhile.
        if (tid < 128) {
            float acc[64];
#pragma unroll
            for (int t = 0; t < 64; t++) acc[t] = vL[t][tid];
#pragma unroll
            for (int s = 0; s < 64; s++) {
                float ds = acc[s];
                vL[s][tid] = ds;  // finalized delta_s
#pragma unroll
                for (int jj = 0; jj < 16; jj++) {
                    float4 a = *(const float4*)&AtL[s][jj * 4];
                    acc[jj * 4 + 0] -= a.x * ds;
                    acc[jj * 4 + 1] -= a.y * ds;
                    acc[jj * 4 + 2] -= a.z * ds;
                    acc[jj * 4 + 3] -= a.w * ds;
                }
            }
        } else {
#pragma unroll 1
            for (int idx = tid - 128; idx < 4096; idx += 384) {
                int r = idx >> 6, c = idx & 63;
                kL[r][c] *= egL[r];
            }
        }
        __syncthreads();

        // ---- P6: O = scale*Gamma*(q.S_in) + M delta
        const float gend = gamL[63];
#pragma unroll 4
        for (int t = 0; t < 64; t++) {
            float p1 = 0.f, p2 = 0.f;
#pragma unroll
            for (int j4 = 0; j4 < 4; j4++) {
                float4 qq = *(const float4*)&qL[t][qd * 16 + j4 * 4];
                p1 += qq.x * S[j4 * 4 + 0] + qq.y * S[j4 * 4 + 1] +
                      qq.z * S[j4 * 4 + 2] + qq.w * S[j4 * 4 + 3];
                float4 mm = *(const float4*)&ML[t][qd * 16 + j4 * 4];
                int s0 = qd * 16 + j4 * 4;
                p2 += mm.x * vL[s0 + 0][dv] + mm.y * vL[s0 + 1][dv] +
                      mm.z * vL[s0 + 2][dv] + mm.w * vL[s0 + 3][dv];
            }
            float p = 0.125f * gamL[t] * p1 + p2;
            p += __shfl_xor(p, 1, 64);
            p += __shfl_xor(p, 2, 64);
            if (qd == 0)
                o[((size_t)b * Tc + t0 + t) * VDIMc + h * DVc + dv] = p;
        }
        // ---- P7: S = exp(c_end) S + K-hat^T delta
#pragma unroll
        for (int j = 0; j < 16; j++) S[j] *= gend;
#pragma unroll 8
        for (int s = 0; s < 64; s++) {
            float d0 = vL[s][dv];
#pragma unroll
            for (int j4 = 0; j4 < 4; j4++) {
                float4 kk = *(const float4*)&kL[s][qd * 16 + j4 * 4];
                S[j4 * 4 + 0] += kk.x * d0;
                S[j4 * 4 + 1] += kk.y * d0;
                S[j4 * 4 + 2] += kk.z * d0;
                S[j4 * 4 + 3] += kk.w * d0;
            }
        }
    }
}

// ---------------------------------------------------------------------------
// Gated RMSNorm: one wave per (b,t,h) row of 128; in-place on o.
// ---------------------------------------------------------------------------
__global__ void __launch_bounds__(256) rms_gate(
    float* __restrict__ o, const float* __restrict__ gg,
    const float* __restrict__ norm_w) {
    const int row = blockIdx.x * 4 + (threadIdx.x >> 6);
    const int lane = threadIdx.x & 63;
    const size_t base = (size_t)row * DVc;
    float2 ov = *(const float2*)&o[base + lane * 2];
    float ss = ov.x * ov.x + ov.y * ov.y;
#pragma unroll
    for (int m = 1; m < 64; m <<= 1) ss += __shfl_xor(ss, m, 64);
    const float f = rsqrtf(ss * (1.f / 128.f) + 1e-5f);
    float2 gv = *(const float2*)&gg[base + lane * 2];
    const float nw0 = norm_w[lane * 2], nw1 = norm_w[lane * 2 + 1];
    float y0 = ov.x * f * nw0 * siluf(gv.x);
    float y1 = ov.y * f * nw1 * siluf(gv.y);
    *(float2*)&o[base + lane * 2] = make_float2(y0, y1);
}

// ---------------------------------------------------------------------------
// Workspace: qb 8.4M + kb 8.4M + vb 16.8M + obuf 16.8M + gbuf/bbuf 0.26M
//            + halo 0.79M  = 51.4M floats = 205.5 MB
// ---------------------------------------------------------------------------
extern "C" void kernel_launch(void* const* d_in, const int* in_sizes, int n_in,
                              void* d_out, int out_size, void* d_ws,
                              size_t ws_size, hipStream_t stream) {
    const float* x = (const float*)d_in[0];
    const float* w_q = (const float*)d_in[1];
    const float* w_k = (const float*)d_in[2];
    const float* w_v = (const float*)d_in[3];
    const float* w_a = (const float*)d_in[4];
    const float* w_b = (const float*)d_in[5];
    const float* w_g = (const float*)d_in[6];
    const float* w_out = (const float*)d_in[7];
    const float* A_log = (const float*)d_in[8];
    const float* dt_bias = (const float*)d_in[9];
    const float* conv_q = (const float*)d_in[10];
    const float* conv_k = (const float*)d_in[11];
    const float* conv_v = (const float*)d_in[12];
    const float* norm_w = (const float*)d_in[13];

    float* ws = (float*)d_ws;
    const size_t M = Mrows;
    float* qb = ws;
    float* kb = qb + M * KDIMc;
    float* vb = kb + M * KDIMc;
    float* obuf = vb + M * VDIMc;
    float* gbuf = obuf + M * VDIMc;
    float* bbuf = gbuf + M * Hc;
    float* halo = bbuf + M * Hc;
    float* gg = qb;  // aliased AFTER the scan (qb+kb contiguous)

    // 1) q/k/v projections
    gemm_f32<<<dim3((M / GBM) * (KDIMc / GBN)), 256, 0, stream>>>(
        x, w_q, qb, M, KDIMc, Dc);
    gemm_f32<<<dim3((M / GBM) * (KDIMc / GBN)), 256, 0, stream>>>(
        x, w_k, kb, M, KDIMc, Dc);
    gemm_f32<<<dim3((M / GBM) * (VDIMc / GBN)), 256, 0, stream>>>(
        x, w_v, vb, M, VDIMc, Dc);

    // 2) a/b projections fused with activation -> g, beta
    ab_proj<<<dim3(M / 4), 256, 0, stream>>>(x, w_a, w_b, A_log, dt_bias, gbuf,
                                             bbuf);

    // 3) conv + silu (+ l2norm for q,k), in place with halo save
    {
        const int nqk = Bc * (Tc / 64 - 1) * 3 * KDIMc;
        const int nv = Bc * (Tc / 64 - 1) * 3 * VDIMc;
        save_halo<KDIMc><<<dim3((nqk + 255) / 256), 256, 0, stream>>>(qb, halo);
        conv_silu_inplace<KDIMc, true>
            <<<dim3(Bc * (Tc / 64) * (KDIMc / 256)), 256, 0, stream>>>(
                qb, conv_q, halo);
        save_halo<KDIMc><<<dim3((nqk + 255) / 256), 256, 0, stream>>>(kb, halo);
        conv_silu_inplace<KDIMc, true>
            <<<dim3(Bc * (Tc / 64) * (KDIMc / 256)), 256, 0, stream>>>(
                kb, conv_k, halo);
        save_halo<VDIMc><<<dim3((nv + 255) / 256), 256, 0, stream>>>(vb, halo);
        conv_silu_inplace<VDIMc, false>
            <<<dim3(Bc * (Tc / 64) * (VDIMc / 256)), 256, 0, stream>>>(
                vb, conv_v, halo);
    }

    // 4) chunked gated delta-rule (WY form)
    chunk_scan<<<dim3(Bc * Hc), 512, 0, stream>>>(qb, kb, vb, gbuf, bbuf,
                                                  obuf);

    // 5) gate projection (after scan so it can alias qb+kb)
    gemm_f32<<<dim3((M / GBM) * (VDIMc / GBN)), 256, 0, stream>>>(
        x, w_g, gg, M, VDIMc, Dc);

    // 6) gated RMSNorm (in place on obuf)
    rms_gate<<<dim3(M * Hc / 4), 256, 0, stream>>>(obuf, gg, norm_w);

    // 7) output projection -> d_out
    gemm_f32<<<dim3((M / GBM) * (Dc / GBN)), 256, 0, stream>>>(
        obuf, w_out, (float*)d_out, M, Dc, VDIMc);
}